// Round 1
// baseline (437.469 us; speedup 1.0000x reference)
//
#include <hip/hip_runtime.h>

// MHA fused forward: B=4, T=2048, C=1024, H=16, DH=64
#define T_SEQ 2048
#define C_DIM 1024
#define H_NUM 16
#define DHD   64
#define B_NUM 4
#define M_ROWS (B_NUM*T_SEQ)   // 8192

typedef __bf16 bf16x8 __attribute__((ext_vector_type(8)));
typedef float  f32x4  __attribute__((ext_vector_type(4)));
typedef unsigned short ushort8 __attribute__((ext_vector_type(8)));
typedef unsigned short ushort4e __attribute__((ext_vector_type(4)));

__device__ __forceinline__ unsigned short f2bf(float f){
  unsigned int u = __builtin_bit_cast(unsigned int, f);
  u += 0x7fffu + ((u >> 16) & 1u);
  return (unsigned short)(u >> 16);
}
__device__ __forceinline__ bf16x8 as_bf(ushort8 u){ return __builtin_bit_cast(bf16x8, u); }

// ---------------- convert x (f32 -> bf16) ----------------
__global__ __launch_bounds__(256) void k_conv_x(const float* __restrict__ x,
                                                unsigned short* __restrict__ xb){
  int i = blockIdx.x*256 + threadIdx.x;   // 2,097,152 threads, 4 floats each
  float4 f = ((const float4*)x)[i];
  ushort4e o;
  o[0]=f2bf(f.x); o[1]=f2bf(f.y); o[2]=f2bf(f.z); o[3]=f2bf(f.w);
  ((ushort4e*)xb)[i] = o;
}

// ---------------- pack weights ----------------
// wt   : (3*C, C) bf16, row n = (m*1024 + h*64 + d), col = c.  wt[n][c] = Wm[h][c][d]
//        (Wq rows scaled by 0.125 = DH^-0.5)
// wot  : (C, C) bf16, wot[n][c] = Wo[c][n]
__global__ __launch_bounds__(256) void k_pack_w(const float* __restrict__ wq,
                                                const float* __restrict__ wk,
                                                const float* __restrict__ wv,
                                                const float* __restrict__ wo,
                                                unsigned short* __restrict__ wt,
                                                unsigned short* __restrict__ wot){
  int idx = blockIdx.x*256 + threadIdx.x;  // 4M threads
  if (idx < 3*C_DIM*C_DIM){
    int nall = idx >> 10; int c = idx & 1023;
    int m = nall >> 10;   int n = nall & 1023;
    int h = n >> 6, d = n & 63;
    const float* w = (m==0) ? wq : (m==1) ? wk : wv;
    float f = w[((size_t)h*C_DIM + c)*DHD + d];
    if (m == 0) f *= 0.125f;
    wt[idx] = f2bf(f);
  } else {
    int j = idx - 3*C_DIM*C_DIM;
    int n = j >> 10, c = j & 1023;
    wot[j] = f2bf(wo[(size_t)c*C_DIM + n]);
  }
}

// ---------------- GEMM: QKV projection ----------------
// C[m][n] = sum_k xb[m][k] * wt[n][k];  m=(b,t), n=(sel,h,d). Scatter to Q/K/V (B,H,T,DH) bf16.
__global__ __launch_bounds__(256) void k_gemm_qkv(const unsigned short* __restrict__ xb,
                                                  const unsigned short* __restrict__ wt,
                                                  unsigned short* __restrict__ qo,
                                                  unsigned short* __restrict__ ko,
                                                  unsigned short* __restrict__ vo){
  __shared__ __align__(16) unsigned short a_lds[128][40];
  __shared__ __align__(16) unsigned short b_lds[128][40];
  int tid = threadIdx.x;
  int lane = tid & 63, wid = tid >> 6;
  int wr = wid >> 1, wc = wid & 1;
  int mbase = blockIdx.y * 128;
  int nbase = blockIdx.x * 128;
  f32x4 acc[4][4] = {};
  for (int kk = 0; kk < C_DIM; kk += 32){
    __syncthreads();
    #pragma unroll
    for (int i = 0; i < 2; i++){
      int c = tid + i*256;
      int row = c >> 2, cc = (c & 3) * 8;
      *(ushort8*)&a_lds[row][cc] = *(const ushort8*)&xb[(size_t)(mbase+row)*C_DIM + kk + cc];
      *(ushort8*)&b_lds[row][cc] = *(const ushort8*)&wt[(size_t)(nbase+row)*C_DIM + kk + cc];
    }
    __syncthreads();
    bf16x8 aF[4], bF[4];
    #pragma unroll
    for (int mb = 0; mb < 4; mb++)
      aF[mb] = as_bf(*(const ushort8*)&a_lds[wr*64 + mb*16 + (lane&15)][(lane>>4)*8]);
    #pragma unroll
    for (int nb = 0; nb < 4; nb++)
      bF[nb] = as_bf(*(const ushort8*)&b_lds[wc*64 + nb*16 + (lane&15)][(lane>>4)*8]);
    #pragma unroll
    for (int mb = 0; mb < 4; mb++)
      #pragma unroll
      for (int nb = 0; nb < 4; nb++)
        acc[mb][nb] = __builtin_amdgcn_mfma_f32_16x16x32_bf16(aF[mb], bF[nb], acc[mb][nb], 0,0,0);
  }
  #pragma unroll
  for (int mb = 0; mb < 4; mb++){
    #pragma unroll
    for (int nb = 0; nb < 4; nb++){
      #pragma unroll
      for (int r = 0; r < 4; r++){
        int gr = mbase + wr*64 + mb*16 + (lane>>4)*4 + r;
        int gc = nbase + wc*64 + nb*16 + (lane&15);
        int b = gr >> 11, t = gr & 2047;
        int sel = gc >> 10, nw = gc & 1023;
        int h = nw >> 6, d = nw & 63;
        unsigned short val = f2bf(acc[mb][nb][r]);
        unsigned short* dst = (sel == 0) ? qo : (sel == 1) ? ko : vo;
        dst[(((size_t)(b*H_NUM + h))*T_SEQ + t)*DHD + d] = val;
      }
    }
  }
}

// ---------------- Flash attention (causal) ----------------
// grid: (T/64, B*H).  4 waves x 16 Q-rows.  K/V tiles of 64 staged in LDS.
__global__ __launch_bounds__(256) void k_flash(const unsigned short* __restrict__ q,
                                               const unsigned short* __restrict__ k,
                                               const unsigned short* __restrict__ v,
                                               unsigned short* __restrict__ o){
  __shared__ __align__(16) unsigned short kt[64][72];
  __shared__ __align__(16) unsigned short vt[64][72];   // vt[d][s]
  __shared__ __align__(16) unsigned short pl[4][16][72];
  int tid = threadIdx.x; int lane = tid & 63; int w = tid >> 6;
  int bh = blockIdx.y; int tbase = blockIdx.x * 64;
  const unsigned short* qb = q + (size_t)bh * T_SEQ * DHD;
  const unsigned short* kb = k + (size_t)bh * T_SEQ * DHD;
  const unsigned short* vb = v + (size_t)bh * T_SEQ * DHD;
  int t0 = tbase + w*16;
  bf16x8 qF[2];
  #pragma unroll
  for (int ks = 0; ks < 2; ks++)
    qF[ks] = as_bf(*(const ushort8*)&qb[(size_t)(t0 + (lane&15))*DHD + ks*32 + (lane>>4)*8]);
  f32x4 acc[4] = {};
  float mrow[4], lrow[4];
  #pragma unroll
  for (int r = 0; r < 4; r++){ mrow[r] = -1e30f; lrow[r] = 0.f; }
  int nkt = (tbase >> 6) + 1;
  for (int kti = 0; kti < nkt; ++kti){
    int kbase = kti << 6;
    __syncthreads();
    #pragma unroll
    for (int i = 0; i < 2; i++){
      int c = tid + i*256; int row = c >> 3, cc = (c & 7)*8;
      *(ushort8*)&kt[row][cc] = *(const ushort8*)&kb[(size_t)(kbase+row)*DHD + cc];
    }
    #pragma unroll
    for (int i = 0; i < 2; i++){
      int c = tid + i*256; int s = c >> 3, dc = (c & 7)*8;
      ushort8 v8 = *(const ushort8*)&vb[(size_t)(kbase+s)*DHD + dc];
      #pragma unroll
      for (int j = 0; j < 8; j++) vt[dc + j][s] = v8[j];
    }
    __syncthreads();
    // S = Q K^T  (scale pre-folded into Wq)
    f32x4 sb[4];
    #pragma unroll
    for (int nb = 0; nb < 4; nb++){
      f32x4 s_ = {0.f,0.f,0.f,0.f};
      #pragma unroll
      for (int ks = 0; ks < 2; ks++){
        bf16x8 kf = as_bf(*(const ushort8*)&kt[nb*16 + (lane&15)][ks*32 + (lane>>4)*8]);
        s_ = __builtin_amdgcn_mfma_f32_16x16x32_bf16(qF[ks], kf, s_, 0,0,0);
      }
      sb[nb] = s_;
    }
    if (kbase == tbase){  // diagonal tile: causal mask
      #pragma unroll
      for (int nb = 0; nb < 4; nb++){
        int sg = nb*16 + (lane&15);
        #pragma unroll
        for (int r = 0; r < 4; r++){
          int tg = w*16 + (lane>>4)*4 + r;
          if (sg > tg) sb[nb][r] = -1e30f;
        }
      }
    }
    // online softmax (rows distributed: 16 lanes of group (lane>>4) hold one row's 64 cols)
    float alpha[4];
    #pragma unroll
    for (int r = 0; r < 4; r++){
      float mx = fmaxf(fmaxf(sb[0][r], sb[1][r]), fmaxf(sb[2][r], sb[3][r]));
      #pragma unroll
      for (int off = 1; off < 16; off <<= 1) mx = fmaxf(mx, __shfl_xor(mx, off));
      float mnew = fmaxf(mrow[r], mx);
      alpha[r] = __expf(mrow[r] - mnew);
      mrow[r] = mnew;
    }
    float rsum[4];
    #pragma unroll
    for (int r = 0; r < 4; r++) rsum[r] = 0.f;
    #pragma unroll
    for (int nb = 0; nb < 4; nb++){
      #pragma unroll
      for (int r = 0; r < 4; r++){
        float p = __expf(sb[nb][r] - mrow[r]);
        sb[nb][r] = p;
        rsum[r] += p;
      }
    }
    #pragma unroll
    for (int r = 0; r < 4; r++){
      float s_ = rsum[r];
      #pragma unroll
      for (int off = 1; off < 16; off <<= 1) s_ += __shfl_xor(s_, off);
      lrow[r] = lrow[r]*alpha[r] + s_;
    }
    // P -> LDS (per-wave region, in-wave DS ordering suffices)
    #pragma unroll
    for (int nb = 0; nb < 4; nb++)
      #pragma unroll
      for (int r = 0; r < 4; r++)
        pl[w][(lane>>4)*4 + r][nb*16 + (lane&15)] = f2bf(sb[nb][r]);
    #pragma unroll
    for (int db = 0; db < 4; db++)
      #pragma unroll
      for (int r = 0; r < 4; r++)
        acc[db][r] *= alpha[r];
    bf16x8 pa[2];
    #pragma unroll
    for (int ks = 0; ks < 2; ks++)
      pa[ks] = as_bf(*(const ushort8*)&pl[w][lane&15][ks*32 + (lane>>4)*8]);
    #pragma unroll
    for (int db = 0; db < 4; db++){
      #pragma unroll
      for (int ks = 0; ks < 2; ks++){
        bf16x8 vf = as_bf(*(const ushort8*)&vt[db*16 + (lane&15)][ks*32 + (lane>>4)*8]);
        acc[db] = __builtin_amdgcn_mfma_f32_16x16x32_bf16(pa[ks], vf, acc[db], 0,0,0);
      }
    }
  }
  int b = bh >> 4, h = bh & 15;
  #pragma unroll
  for (int db = 0; db < 4; db++){
    #pragma unroll
    for (int r = 0; r < 4; r++){
      int t = t0 + (lane>>4)*4 + r;
      float oo = acc[db][r] / lrow[r];
      o[((size_t)(b*T_SEQ + t))*C_DIM + h*DHD + db*16 + (lane&15)] = f2bf(oo);
    }
  }
}

// ---------------- GEMM: output projection + bias ----------------
__global__ __launch_bounds__(256) void k_gemm_proj(const unsigned short* __restrict__ ab,
                                                   const unsigned short* __restrict__ wot,
                                                   const float* __restrict__ bo,
                                                   float* __restrict__ out){
  __shared__ __align__(16) unsigned short a_lds[128][40];
  __shared__ __align__(16) unsigned short b_lds[128][40];
  int tid = threadIdx.x;
  int lane = tid & 63, wid = tid >> 6;
  int wr = wid >> 1, wc = wid & 1;
  int mbase = blockIdx.y * 128;
  int nbase = blockIdx.x * 128;
  f32x4 acc[4][4] = {};
  for (int kk = 0; kk < C_DIM; kk += 32){
    __syncthreads();
    #pragma unroll
    for (int i = 0; i < 2; i++){
      int c = tid + i*256;
      int row = c >> 2, cc = (c & 3) * 8;
      *(ushort8*)&a_lds[row][cc] = *(const ushort8*)&ab[(size_t)(mbase+row)*C_DIM + kk + cc];
      *(ushort8*)&b_lds[row][cc] = *(const ushort8*)&wot[(size_t)(nbase+row)*C_DIM + kk + cc];
    }
    __syncthreads();
    bf16x8 aF[4], bF[4];
    #pragma unroll
    for (int mb = 0; mb < 4; mb++)
      aF[mb] = as_bf(*(const ushort8*)&a_lds[wr*64 + mb*16 + (lane&15)][(lane>>4)*8]);
    #pragma unroll
    for (int nb = 0; nb < 4; nb++)
      bF[nb] = as_bf(*(const ushort8*)&b_lds[wc*64 + nb*16 + (lane&15)][(lane>>4)*8]);
    #pragma unroll
    for (int mb = 0; mb < 4; mb++)
      #pragma unroll
      for (int nb = 0; nb < 4; nb++)
        acc[mb][nb] = __builtin_amdgcn_mfma_f32_16x16x32_bf16(aF[mb], bF[nb], acc[mb][nb], 0,0,0);
  }
  #pragma unroll
  for (int mb = 0; mb < 4; mb++){
    #pragma unroll
    for (int nb = 0; nb < 4; nb++){
      #pragma unroll
      for (int r = 0; r < 4; r++){
        int gr = mbase + wr*64 + mb*16 + (lane>>4)*4 + r;
        int gc = nbase + wc*64 + nb*16 + (lane&15);
        out[(size_t)gr*C_DIM + gc] = acc[mb][nb][r] + bo[gc];
      }
    }
  }
}

extern "C" void kernel_launch(void* const* d_in, const int* in_sizes, int n_in,
                              void* d_out, int out_size, void* d_ws, size_t ws_size,
                              hipStream_t stream){
  const float* x  = (const float*)d_in[0];
  const float* Wq = (const float*)d_in[1];
  const float* Wk = (const float*)d_in[2];
  const float* Wv = (const float*)d_in[3];
  const float* Wo = (const float*)d_in[4];
  const float* bo = (const float*)d_in[5];
  float* out = (float*)d_out;

  char* p = (char*)d_ws;
  unsigned short* xb  = (unsigned short*)p; p += (size_t)M_ROWS*C_DIM*2;   // 16MB
  unsigned short* wt  = (unsigned short*)p; p += (size_t)3*C_DIM*C_DIM*2;  // 6MB
  unsigned short* wot = (unsigned short*)p; p += (size_t)C_DIM*C_DIM*2;    // 2MB
  unsigned short* Qb  = (unsigned short*)p; p += (size_t)M_ROWS*C_DIM*2;   // 16MB
  unsigned short* Kb  = (unsigned short*)p; p += (size_t)M_ROWS*C_DIM*2;   // 16MB
  unsigned short* Vb  = (unsigned short*)p; p += (size_t)M_ROWS*C_DIM*2;   // 16MB
  unsigned short* attn = xb;  // reuse: xb dead after k_gemm_qkv

  hipLaunchKernelGGL(k_conv_x, dim3(M_ROWS*C_DIM/4/256), dim3(256), 0, stream, x, xb);
  hipLaunchKernelGGL(k_pack_w, dim3(4*C_DIM*C_DIM/256), dim3(256), 0, stream,
                     Wq, Wk, Wv, Wo, wt, wot);
  hipLaunchKernelGGL(k_gemm_qkv, dim3(3*C_DIM/128, M_ROWS/128), dim3(256), 0, stream,
                     xb, wt, Qb, Kb, Vb);
  hipLaunchKernelGGL(k_flash, dim3(T_SEQ/64, B_NUM*H_NUM), dim3(256), 0, stream,
                     Qb, Kb, Vb, attn);
  hipLaunchKernelGGL(k_gemm_proj, dim3(C_DIM/128, M_ROWS/128), dim3(256), 0, stream,
                     attn, wot, bo, out);
}

// Round 2
// 316.073 us; speedup vs baseline: 1.3841x; 1.3841x over previous
//
#include <hip/hip_runtime.h>

// MHA fused forward: B=4, T=2048, C=1024, H=16, DH=64
#define T_SEQ 2048
#define C_DIM 1024
#define H_NUM 16
#define DHD   64
#define B_NUM 4
#define M_ROWS (B_NUM*T_SEQ)   // 8192

typedef __bf16 bf16x8 __attribute__((ext_vector_type(8)));
typedef float  f32x4  __attribute__((ext_vector_type(4)));
typedef unsigned short ushort8 __attribute__((ext_vector_type(8)));
typedef unsigned short ushort4e __attribute__((ext_vector_type(4)));

__device__ __forceinline__ unsigned short f2bf(float f){
  unsigned int u = __builtin_bit_cast(unsigned int, f);
  u += 0x7fffu + ((u >> 16) & 1u);
  return (unsigned short)(u >> 16);
}
__device__ __forceinline__ bf16x8 as_bf(ushort8 u){ return __builtin_bit_cast(bf16x8, u); }

// ---------------- convert x (f32 -> bf16) ----------------
__global__ __launch_bounds__(256) void k_conv_x(const float* __restrict__ x,
                                                unsigned short* __restrict__ xb){
  int i = blockIdx.x*256 + threadIdx.x;
  float4 f = ((const float4*)x)[i];
  ushort4e o;
  o[0]=f2bf(f.x); o[1]=f2bf(f.y); o[2]=f2bf(f.z); o[3]=f2bf(f.w);
  ((ushort4e*)xb)[i] = o;
}

// ---------------- pack weights ----------------
__global__ __launch_bounds__(256) void k_pack_w(const float* __restrict__ wq,
                                                const float* __restrict__ wk,
                                                const float* __restrict__ wv,
                                                const float* __restrict__ wo,
                                                unsigned short* __restrict__ wt,
                                                unsigned short* __restrict__ wot){
  int idx = blockIdx.x*256 + threadIdx.x;
  if (idx < 3*C_DIM*C_DIM){
    int nall = idx >> 10; int c = idx & 1023;
    int m = nall >> 10;   int n = nall & 1023;
    int h = n >> 6, d = n & 63;
    const float* w = (m==0) ? wq : (m==1) ? wk : wv;
    float f = w[((size_t)h*C_DIM + c)*DHD + d];
    if (m == 0) f *= 0.125f;
    wt[idx] = f2bf(f);
  } else {
    int j = idx - 3*C_DIM*C_DIM;
    int n = j >> 10, c = j & 1023;
    wot[j] = f2bf(wo[(size_t)c*C_DIM + n]);
  }
}

// ---------------- GEMM: QKV projection ----------------
__global__ __launch_bounds__(256) void k_gemm_qkv(const unsigned short* __restrict__ xb,
                                                  const unsigned short* __restrict__ wt,
                                                  unsigned short* __restrict__ qo,
                                                  unsigned short* __restrict__ ko,
                                                  unsigned short* __restrict__ vo){
  __shared__ __align__(16) unsigned short a_lds[128][40];
  __shared__ __align__(16) unsigned short b_lds[128][40];
  int tid = threadIdx.x;
  int lane = tid & 63, wid = tid >> 6;
  int wr = wid >> 1, wc = wid & 1;
  int mbase = blockIdx.y * 128;
  int nbase = blockIdx.x * 128;
  f32x4 acc[4][4] = {};
  for (int kk = 0; kk < C_DIM; kk += 32){
    __syncthreads();
    #pragma unroll
    for (int i = 0; i < 2; i++){
      int c = tid + i*256;
      int row = c >> 2, cc = (c & 3) * 8;
      *(ushort8*)&a_lds[row][cc] = *(const ushort8*)&xb[(size_t)(mbase+row)*C_DIM + kk + cc];
      *(ushort8*)&b_lds[row][cc] = *(const ushort8*)&wt[(size_t)(nbase+row)*C_DIM + kk + cc];
    }
    __syncthreads();
    bf16x8 aF[4], bF[4];
    #pragma unroll
    for (int mb = 0; mb < 4; mb++)
      aF[mb] = as_bf(*(const ushort8*)&a_lds[wr*64 + mb*16 + (lane&15)][(lane>>4)*8]);
    #pragma unroll
    for (int nb = 0; nb < 4; nb++)
      bF[nb] = as_bf(*(const ushort8*)&b_lds[wc*64 + nb*16 + (lane&15)][(lane>>4)*8]);
    #pragma unroll
    for (int mb = 0; mb < 4; mb++)
      #pragma unroll
      for (int nb = 0; nb < 4; nb++)
        acc[mb][nb] = __builtin_amdgcn_mfma_f32_16x16x32_bf16(aF[mb], bF[nb], acc[mb][nb], 0,0,0);
  }
  #pragma unroll
  for (int mb = 0; mb < 4; mb++){
    #pragma unroll
    for (int nb = 0; nb < 4; nb++){
      #pragma unroll
      for (int r = 0; r < 4; r++){
        int gr = mbase + wr*64 + mb*16 + (lane>>4)*4 + r;
        int gc = nbase + wc*64 + nb*16 + (lane&15);
        int b = gr >> 11, t = gr & 2047;
        int sel = gc >> 10, nw = gc & 1023;
        int h = nw >> 6, d = nw & 63;
        unsigned short val = f2bf(acc[mb][nb][r]);
        unsigned short* dst = (sel == 0) ? qo : (sel == 1) ? ko : vo;
        dst[(((size_t)(b*H_NUM + h))*T_SEQ + t)*DHD + d] = val;
      }
    }
  }
}

// ---------------- V transpose: (bh, t, d) -> (bh, d, t) ----------------
// XOR-swizzled LDS transpose; coalesced global reads AND writes.
__global__ __launch_bounds__(256) void k_tr_v(const unsigned short* __restrict__ vsrc,
                                              unsigned short* __restrict__ vdst){
  __shared__ __align__(16) unsigned short vr[64][72];
  int tid = threadIdx.x;
  int bh = blockIdx.y; int tbase = blockIdx.x * 64;
  const unsigned short* vb = vsrc + (size_t)bh * T_SEQ * DHD;
  unsigned short* vo = vdst + (size_t)bh * DHD * T_SEQ;
  #pragma unroll
  for (int i = 0; i < 2; i++){
    int id = tid + i*256;
    int row = id >> 3, c8 = (id & 7) << 3;
    // element V[row][d] stored at vr[row][d ^ ((row>>3)<<3)]
    *(ushort8*)&vr[row][c8 ^ ((row >> 3) << 3)] =
        *(const ushort8*)&vb[(size_t)(tbase + row)*DHD + c8];
  }
  __syncthreads();
  #pragma unroll
  for (int i = 0; i < 2; i++){
    int id = tid + i*256;
    int d = id >> 3, oc = id & 7;
    ushort8 out;
    #pragma unroll
    for (int j = 0; j < 8; j++){
      int t = oc*8 + j;                 // t>>3 == oc
      out[j] = vr[t][d ^ (oc << 3)];
    }
    *(ushort8*)&vo[(size_t)d*T_SEQ + tbase + oc*8] = out;
  }
}

// ---------------- Flash attention (causal), swapped-QK^T ----------------
// grid: (T/128, B*H). 4 waves x 32 Q-rows. KVBLK=64. V^T pre-transposed in global.
__global__ __launch_bounds__(256) void k_flash(const unsigned short* __restrict__ q,
                                               const unsigned short* __restrict__ k,
                                               const unsigned short* __restrict__ vtg,
                                               unsigned short* __restrict__ o){
  __shared__ __align__(16) unsigned short kt[64][72];   // [s][d]
  __shared__ __align__(16) unsigned short vt[64][72];   // [d][s]  (from V^T global)
  __shared__ __align__(16) unsigned short pl[4][32][72];// per-wave P^T rows=t cols=s
  int tid = threadIdx.x; int lane = tid & 63; int w = tid >> 6;
  int g = lane >> 4, tl = lane & 15;
  int bh = blockIdx.y; int tbase = blockIdx.x * 128;
  const unsigned short* qb = q   + (size_t)bh * T_SEQ * DHD;
  const unsigned short* kb = k   + (size_t)bh * T_SEQ * DHD;
  const unsigned short* vb = vtg + (size_t)bh * DHD * T_SEQ;
  int trow0 = tbase + w*32;
  // Q as B-operand: lane holds Q[t][d], t=lane&15, d=32ks+8g+j
  bf16x8 qF[2][2];
  #pragma unroll
  for (int tf = 0; tf < 2; tf++)
    #pragma unroll
    for (int ks = 0; ks < 2; ks++)
      qF[tf][ks] = as_bf(*(const ushort8*)&qb[(size_t)(trow0 + tf*16 + tl)*DHD + ks*32 + g*8]);
  f32x4 acc[2][4] = {};
  float mreg[2] = {-1e30f, -1e30f}, lreg[2] = {0.f, 0.f};
  int tmax = trow0 + 31;
  int nkt = (tbase >> 6) + 2;
  for (int kti = 0; kti < nkt; ++kti){
    int kbase = kti << 6;
    __syncthreads();
    #pragma unroll
    for (int i = 0; i < 2; i++){
      int id = tid + i*256;
      int row = id >> 3, c8 = (id & 7) << 3;
      *(ushort8*)&kt[row][c8] = *(const ushort8*)&kb[(size_t)(kbase+row)*DHD + c8];
      *(ushort8*)&vt[row][c8] = *(const ushort8*)&vb[(size_t)row*T_SEQ + kbase + c8];
    }
    __syncthreads();
    if (kbase <= tmax){
      // S^T = K x Q^T : lane holds S^T[s][t], s = sf*16+4g+r, t = tl
      f32x4 st[2][4];
      #pragma unroll
      for (int tf = 0; tf < 2; tf++)
        #pragma unroll
        for (int sf = 0; sf < 4; sf++)
          st[tf][sf] = f32x4{0.f,0.f,0.f,0.f};
      #pragma unroll
      for (int sf = 0; sf < 4; sf++){
        bf16x8 kf0 = as_bf(*(const ushort8*)&kt[sf*16 + tl][g*8]);
        bf16x8 kf1 = as_bf(*(const ushort8*)&kt[sf*16 + tl][32 + g*8]);
        #pragma unroll
        for (int tf = 0; tf < 2; tf++){
          st[tf][sf] = __builtin_amdgcn_mfma_f32_16x16x32_bf16(kf0, qF[tf][0], st[tf][sf], 0,0,0);
          st[tf][sf] = __builtin_amdgcn_mfma_f32_16x16x32_bf16(kf1, qF[tf][1], st[tf][sf], 0,0,0);
        }
      }
      if (kbase + 63 > trow0){  // causal mask on (near-)diagonal tiles
        #pragma unroll
        for (int tf = 0; tf < 2; tf++){
          int tg = trow0 + tf*16 + tl;
          #pragma unroll
          for (int sf = 0; sf < 4; sf++)
            #pragma unroll
            for (int r = 0; r < 4; r++)
              if (kbase + sf*16 + g*4 + r > tg) st[tf][sf][r] = -1e30f;
        }
      }
      #pragma unroll
      for (int tf = 0; tf < 2; tf++){
        float mloc = -1e30f;
        #pragma unroll
        for (int sf = 0; sf < 4; sf++)
          #pragma unroll
          for (int r = 0; r < 4; r++) mloc = fmaxf(mloc, st[tf][sf][r]);
        mloc = fmaxf(mloc, __shfl_xor(mloc, 16));
        mloc = fmaxf(mloc, __shfl_xor(mloc, 32));
        float mnew = fmaxf(mreg[tf], mloc);
        float alpha = __expf(mreg[tf] - mnew);
        mreg[tf] = mnew;
        float sum = 0.f;
        #pragma unroll
        for (int sf = 0; sf < 4; sf++)
          #pragma unroll
          for (int r = 0; r < 4; r++){
            float p = __expf(st[tf][sf][r] - mnew);
            st[tf][sf][r] = p;
            sum += p;
          }
        sum += __shfl_xor(sum, 16);
        sum += __shfl_xor(sum, 32);
        lreg[tf] = lreg[tf]*alpha + sum;
        #pragma unroll
        for (int df = 0; df < 4; df++)
          #pragma unroll
          for (int r = 0; r < 4; r++) acc[tf][df][r] *= alpha;
        #pragma unroll
        for (int sf = 0; sf < 4; sf++){
          ushort4e pk;
          #pragma unroll
          for (int r = 0; r < 4; r++) pk[r] = f2bf(st[tf][sf][r]);
          *(ushort4e*)&pl[w][tf*16 + tl][sf*16 + g*4] = pk;
        }
      }
      // P^T as B-operand: lane holds P^T[s][t], t = tl, s = 32ks+8g+j
      bf16x8 pa[2][2];
      #pragma unroll
      for (int tf = 0; tf < 2; tf++)
        #pragma unroll
        for (int ks = 0; ks < 2; ks++)
          pa[tf][ks] = as_bf(*(const ushort8*)&pl[w][tf*16 + tl][ks*32 + g*8]);
      // O^T[d][t] += V^T[d][s] * P^T[s][t]
      #pragma unroll
      for (int df = 0; df < 4; df++){
        bf16x8 vf0 = as_bf(*(const ushort8*)&vt[df*16 + tl][g*8]);
        bf16x8 vf1 = as_bf(*(const ushort8*)&vt[df*16 + tl][32 + g*8]);
        #pragma unroll
        for (int tf = 0; tf < 2; tf++){
          acc[tf][df] = __builtin_amdgcn_mfma_f32_16x16x32_bf16(vf0, pa[tf][0], acc[tf][df], 0,0,0);
          acc[tf][df] = __builtin_amdgcn_mfma_f32_16x16x32_bf16(vf1, pa[tf][1], acc[tf][df], 0,0,0);
        }
      }
    }
  }
  int b = bh >> 4, h = bh & 15;
  #pragma unroll
  for (int tf = 0; tf < 2; tf++){
    float inv = 1.f / lreg[tf];
    int tg = trow0 + tf*16 + tl;
    #pragma unroll
    for (int df = 0; df < 4; df++)
      #pragma unroll
      for (int r = 0; r < 4; r++){
        int d = df*16 + g*4 + r;
        o[((size_t)(b*T_SEQ + tg))*C_DIM + h*DHD + d] = f2bf(acc[tf][df][r] * inv);
      }
  }
}

// ---------------- GEMM: output projection + bias ----------------
__global__ __launch_bounds__(256) void k_gemm_proj(const unsigned short* __restrict__ ab,
                                                   const unsigned short* __restrict__ wot,
                                                   const float* __restrict__ bo,
                                                   float* __restrict__ out){
  __shared__ __align__(16) unsigned short a_lds[128][40];
  __shared__ __align__(16) unsigned short b_lds[128][40];
  int tid = threadIdx.x;
  int lane = tid & 63, wid = tid >> 6;
  int wr = wid >> 1, wc = wid & 1;
  int mbase = blockIdx.y * 128;
  int nbase = blockIdx.x * 128;
  f32x4 acc[4][4] = {};
  for (int kk = 0; kk < C_DIM; kk += 32){
    __syncthreads();
    #pragma unroll
    for (int i = 0; i < 2; i++){
      int c = tid + i*256;
      int row = c >> 2, cc = (c & 3) * 8;
      *(ushort8*)&a_lds[row][cc] = *(const ushort8*)&ab[(size_t)(mbase+row)*C_DIM + kk + cc];
      *(ushort8*)&b_lds[row][cc] = *(const ushort8*)&wot[(size_t)(nbase+row)*C_DIM + kk + cc];
    }
    __syncthreads();
    bf16x8 aF[4], bF[4];
    #pragma unroll
    for (int mb = 0; mb < 4; mb++)
      aF[mb] = as_bf(*(const ushort8*)&a_lds[wr*64 + mb*16 + (lane&15)][(lane>>4)*8]);
    #pragma unroll
    for (int nb = 0; nb < 4; nb++)
      bF[nb] = as_bf(*(const ushort8*)&b_lds[wc*64 + nb*16 + (lane&15)][(lane>>4)*8]);
    #pragma unroll
    for (int mb = 0; mb < 4; mb++)
      #pragma unroll
      for (int nb = 0; nb < 4; nb++)
        acc[mb][nb] = __builtin_amdgcn_mfma_f32_16x16x32_bf16(aF[mb], bF[nb], acc[mb][nb], 0,0,0);
  }
  #pragma unroll
  for (int mb = 0; mb < 4; mb++){
    #pragma unroll
    for (int nb = 0; nb < 4; nb++){
      #pragma unroll
      for (int r = 0; r < 4; r++){
        int gr = mbase + wr*64 + mb*16 + (lane>>4)*4 + r;
        int gc = nbase + wc*64 + nb*16 + (lane&15);
        out[(size_t)gr*C_DIM + gc] = acc[mb][nb][r] + bo[gc];
      }
    }
  }
}

extern "C" void kernel_launch(void* const* d_in, const int* in_sizes, int n_in,
                              void* d_out, int out_size, void* d_ws, size_t ws_size,
                              hipStream_t stream){
  const float* x  = (const float*)d_in[0];
  const float* Wq = (const float*)d_in[1];
  const float* Wk = (const float*)d_in[2];
  const float* Wv = (const float*)d_in[3];
  const float* Wo = (const float*)d_in[4];
  const float* bo = (const float*)d_in[5];
  float* out = (float*)d_out;

  char* p = (char*)d_ws;
  unsigned short* xb  = (unsigned short*)p; p += (size_t)M_ROWS*C_DIM*2;   // 16MB
  unsigned short* wt  = (unsigned short*)p; p += (size_t)3*C_DIM*C_DIM*2;  // 6MB
  unsigned short* wot = (unsigned short*)p; p += (size_t)C_DIM*C_DIM*2;    // 2MB
  unsigned short* Qb  = (unsigned short*)p; p += (size_t)M_ROWS*C_DIM*2;   // 16MB
  unsigned short* Kb  = (unsigned short*)p; p += (size_t)M_ROWS*C_DIM*2;   // 16MB
  unsigned short* Vb  = (unsigned short*)p; p += (size_t)M_ROWS*C_DIM*2;   // 16MB
  unsigned short* Vtr  = xb;   // reuse: xb dead after k_gemm_qkv
  unsigned short* attn = Vb;   // reuse: Vb dead after k_tr_v

  hipLaunchKernelGGL(k_conv_x, dim3(M_ROWS*C_DIM/4/256), dim3(256), 0, stream, x, xb);
  hipLaunchKernelGGL(k_pack_w, dim3(4*C_DIM*C_DIM/256), dim3(256), 0, stream,
                     Wq, Wk, Wv, Wo, wt, wot);
  hipLaunchKernelGGL(k_gemm_qkv, dim3(3*C_DIM/128, M_ROWS/128), dim3(256), 0, stream,
                     xb, wt, Qb, Kb, Vb);
  hipLaunchKernelGGL(k_tr_v, dim3(T_SEQ/64, B_NUM*H_NUM), dim3(256), 0, stream, Vb, Vtr);
  hipLaunchKernelGGL(k_flash, dim3(T_SEQ/128, B_NUM*H_NUM), dim3(256), 0, stream,
                     Qb, Kb, Vtr, attn);
  hipLaunchKernelGGL(k_gemm_proj, dim3(C_DIM/128, M_ROWS/128), dim3(256), 0, stream,
                     attn, wot, bo, out);
}

// Round 4
// 201.910 us; speedup vs baseline: 2.1667x; 1.5654x over previous
//
#include <hip/hip_runtime.h>

// MHA fused forward: B=4, T=2048, C=1024, H=16, DH=64
#define T_SEQ 2048
#define C_DIM 1024
#define H_NUM 16
#define DHD   64
#define B_NUM 4
#define M_ROWS (B_NUM*T_SEQ)   // 8192

typedef __bf16 bf16x8 __attribute__((ext_vector_type(8)));
typedef float  f32x4  __attribute__((ext_vector_type(4)));
typedef unsigned short ushort8 __attribute__((ext_vector_type(8)));
typedef unsigned short ushort4e __attribute__((ext_vector_type(4)));

__device__ __forceinline__ unsigned short f2b(float f){
  return __builtin_bit_cast(unsigned short, (__bf16)f);
}
__device__ __forceinline__ bf16x8 as_bf(ushort8 u){ return __builtin_bit_cast(bf16x8, u); }
__device__ __forceinline__ float exp2fast(float x){ return __builtin_amdgcn_exp2f(x); }

__device__ __forceinline__ void gload16(const void* g, void* l){
  __builtin_amdgcn_global_load_lds(
      (const __attribute__((address_space(1))) void*)g,
      (__attribute__((address_space(3))) void*)l, 16, 0, 0);
}

// ---------------- convert x (f32 -> bf16) ----------------
__global__ __launch_bounds__(256) void k_conv_x(const float* __restrict__ x,
                                                unsigned short* __restrict__ xb){
  int i = blockIdx.x*256 + threadIdx.x;
  float4 f = ((const float4*)x)[i];
  ushort4e o;
  o[0]=f2b(f.x); o[1]=f2b(f.y); o[2]=f2b(f.z); o[3]=f2b(f.w);
  ((ushort4e*)xb)[i] = o;
}

// ---------------- pack weights ----------------
// wt: (3*C, C) bf16 rows n=(m,h,d), cols c. Wq rows scaled by 0.125*log2(e)
// (softmax computed in exp2 domain). wot: (C,C) wot[n][c] = Wo[c][n].
__global__ __launch_bounds__(256) void k_pack_w(const float* __restrict__ wq,
                                                const float* __restrict__ wk,
                                                const float* __restrict__ wv,
                                                const float* __restrict__ wo,
                                                unsigned short* __restrict__ wt,
                                                unsigned short* __restrict__ wot){
  int idx = blockIdx.x*256 + threadIdx.x;
  if (idx < 3*C_DIM*C_DIM){
    int nall = idx >> 10; int c = idx & 1023;
    int m = nall >> 10;   int n = nall & 1023;
    int h = n >> 6, d = n & 63;
    const float* w = (m==0) ? wq : (m==1) ? wk : wv;
    float f = w[((size_t)h*C_DIM + c)*DHD + d];
    if (m == 0) f *= 0.125f * 1.4426950408889634f;  // DH^-0.5 * log2(e)
    wt[idx] = f2b(f);
  } else {
    int j = idx - 3*C_DIM*C_DIM;
    int n = j >> 10, c = j & 1023;
    wot[j] = f2b(wo[(size_t)c*C_DIM + n]);
  }
}

// ---------------- GEMM (m97-structure): BK=64, global_load_lds, XOR swizzle ----------------
// C[m][n] = sum_k A[m][k]*Bt[n][k]
__global__ __launch_bounds__(256) void k_gemm_qkv(const unsigned short* __restrict__ xb,
                                                  const unsigned short* __restrict__ wt,
                                                  unsigned short* __restrict__ qo,
                                                  unsigned short* __restrict__ ko,
                                                  unsigned short* __restrict__ vo){
  __shared__ __align__(16) unsigned short a_lds[128*64];
  __shared__ __align__(16) unsigned short b_lds[128*64];
  const int tid = threadIdx.x, lane = tid & 63, wid = tid >> 6;
  const int g = lane >> 4, tl = lane & 15;
  const int wr = wid >> 1, wc = wid & 1;
  const int mbase = blockIdx.y * 128, nbase = blockIdx.x * 128;
  f32x4 acc[4][4] = {};
  for (int kk = 0; kk < C_DIM; kk += 64){
    __syncthreads();
    #pragma unroll
    for (int i = 0; i < 4; i++){
      const int brow = (wid*4 + i)*8;
      const int row  = brow + (lane >> 3);
      const int jj   = (lane & 7) ^ (row & 7);
      gload16(&xb[(size_t)(mbase+row)*C_DIM + kk + jj*8], &a_lds[brow*64]);
      gload16(&wt[(size_t)(nbase+row)*C_DIM + kk + jj*8], &b_lds[brow*64]);
    }
    __syncthreads();
    bf16x8 aF[4][2], bF[4][2];
    #pragma unroll
    for (int mb = 0; mb < 4; mb++){
      const int row = wr*64 + mb*16 + tl; const int s7 = row & 7;
      aF[mb][0] = as_bf(*(const ushort8*)&a_lds[row*64 + ((g     ^ s7)*8)]);
      aF[mb][1] = as_bf(*(const ushort8*)&a_lds[row*64 + (((4+g) ^ s7)*8)]);
    }
    #pragma unroll
    for (int nb = 0; nb < 4; nb++){
      const int row = wc*64 + nb*16 + tl; const int s7 = row & 7;
      bF[nb][0] = as_bf(*(const ushort8*)&b_lds[row*64 + ((g     ^ s7)*8)]);
      bF[nb][1] = as_bf(*(const ushort8*)&b_lds[row*64 + (((4+g) ^ s7)*8)]);
    }
    #pragma unroll
    for (int mb = 0; mb < 4; mb++)
      #pragma unroll
      for (int nb = 0; nb < 4; nb++){
        acc[mb][nb] = __builtin_amdgcn_mfma_f32_16x16x32_bf16(aF[mb][0], bF[nb][0], acc[mb][nb], 0,0,0);
        acc[mb][nb] = __builtin_amdgcn_mfma_f32_16x16x32_bf16(aF[mb][1], bF[nb][1], acc[mb][nb], 0,0,0);
      }
  }
  #pragma unroll
  for (int mb = 0; mb < 4; mb++){
    #pragma unroll
    for (int nb = 0; nb < 4; nb++){
      #pragma unroll
      for (int r = 0; r < 4; r++){
        int gr = mbase + wr*64 + mb*16 + g*4 + r;
        int gc = nbase + wc*64 + nb*16 + tl;
        int b = gr >> 11, t = gr & 2047;
        int sel = gc >> 10, nw = gc & 1023;
        int h = nw >> 6, d = nw & 63;
        unsigned short* dst = (sel == 0) ? qo : (sel == 1) ? ko : vo;
        dst[(((size_t)(b*H_NUM + h))*T_SEQ + t)*DHD + d] = f2b(acc[mb][nb][r]);
      }
    }
  }
}

// ---------------- V transpose: (bh, t, d) -> (bh, d, t) ----------------
__global__ __launch_bounds__(256) void k_tr_v(const unsigned short* __restrict__ vsrc,
                                              unsigned short* __restrict__ vdst){
  __shared__ __align__(16) unsigned short vr[64][72];
  int tid = threadIdx.x;
  int bh = blockIdx.y; int tbase = blockIdx.x * 64;
  const unsigned short* vb = vsrc + (size_t)bh * T_SEQ * DHD;
  unsigned short* vo = vdst + (size_t)bh * DHD * T_SEQ;
  #pragma unroll
  for (int i = 0; i < 2; i++){
    int id = tid + i*256;
    int row = id >> 3, c8 = (id & 7) << 3;
    *(ushort8*)&vr[row][c8 ^ ((row >> 3) << 3)] =
        *(const ushort8*)&vb[(size_t)(tbase + row)*DHD + c8];
  }
  __syncthreads();
  #pragma unroll
  for (int i = 0; i < 2; i++){
    int id = tid + i*256;
    int d = id >> 3, oc = id & 7;
    ushort8 out;
    #pragma unroll
    for (int j = 0; j < 8; j++){
      int t = oc*8 + j;
      out[j] = vr[t][d ^ (oc << 3)];
    }
    *(ushort8*)&vo[(size_t)d*T_SEQ + tbase + oc*8] = out;
  }
}

// ---------------- Flash attention (causal), balanced + pipelined ----------------
// grid: (8, B*H). Each block does Q-tile pair {bx, 15-bx} (equal 34 tile-iters).
// 4 waves x 32 Q-rows per tile; KVBLK=64; double-buffered LDS staged by
// global_load_lds with pre-swizzled source; exp2-domain softmax + defer-max.
__global__ __launch_bounds__(256) void k_flash(const unsigned short* __restrict__ q,
                                               const unsigned short* __restrict__ k,
                                               const unsigned short* __restrict__ vtg,
                                               unsigned short* __restrict__ o){
  __shared__ __align__(16) unsigned short kbufs[2][64*64];
  __shared__ __align__(16) unsigned short vbufs[2][64*64];
  __shared__ __align__(16) unsigned short pl[4][32][72];
  const int tid = threadIdx.x, lane = tid & 63, w = tid >> 6;
  const int g = lane >> 4, tl = lane & 15;
  const int bh = blockIdx.y, bx = blockIdx.x;
  const int b = bh >> 4, h = bh & 15;
  const unsigned short* qb = q   + (size_t)bh * T_SEQ * DHD;
  const unsigned short* kb = k   + (size_t)bh * T_SEQ * DHD;
  const unsigned short* vb = vtg + (size_t)bh * (size_t)DHD * T_SEQ;
  const int lrow = lane >> 3, lj = lane & 7;

  for (int pass = 0; pass < 2; ++pass){
    const int qt = pass ? (15 - bx) : bx;
    const int tbase = qt * 128;
    const int trow0 = tbase + w * 32;
    const int tmax = trow0 + 31;
    bf16x8 qF[2][2];
    #pragma unroll
    for (int tf = 0; tf < 2; tf++)
      #pragma unroll
      for (int ks = 0; ks < 2; ks++)
        qF[tf][ks] = as_bf(*(const ushort8*)&qb[(size_t)(trow0 + tf*16 + tl)*DHD + ks*32 + g*8]);
    f32x4 acc[2][4] = {};
    float mreg[2] = {-1e30f, -1e30f}, lreg[2] = {0.f, 0.f};
    const int nkt = 2*qt + 2;
    // prologue: stage tile 0 into buf 0
    #pragma unroll
    for (int i = 0; i < 2; i++){
      const int brow = w*16 + i*8;
      const int row = brow + lrow;
      const int jj = lj ^ (row & 7);
      gload16(&kb[(size_t)row*DHD + jj*8],   &kbufs[0][brow*64]);
      gload16(&vb[(size_t)row*T_SEQ + jj*8], &vbufs[0][brow*64]);
    }
    __syncthreads();
    for (int kti = 0; kti < nkt; ++kti){
      const int cur = kti & 1;
      const int kbase = kti * 64;
      if (kti + 1 < nkt){
        const int kb2 = kbase + 64;
        #pragma unroll
        for (int i = 0; i < 2; i++){
          const int brow = w*16 + i*8;
          const int row = brow + lrow;
          const int jj = lj ^ (row & 7);
          gload16(&kb[(size_t)(kb2+row)*DHD + jj*8],       &kbufs[cur^1][brow*64]);
          gload16(&vb[(size_t)row*T_SEQ + kb2 + jj*8],     &vbufs[cur^1][brow*64]);
        }
      }
      if (kbase <= tmax){
        const unsigned short* kcur = kbufs[cur];
        const unsigned short* vcur = vbufs[cur];
        const int s7 = tl & 7;
        f32x4 st[2][4] = {};
        #pragma unroll
        for (int sf = 0; sf < 4; sf++){
          const int row = sf*16 + tl;
          bf16x8 kf0 = as_bf(*(const ushort8*)&kcur[row*64 + ((g     ^ s7)*8)]);
          bf16x8 kf1 = as_bf(*(const ushort8*)&kcur[row*64 + (((4+g) ^ s7)*8)]);
          #pragma unroll
          for (int tf = 0; tf < 2; tf++){
            st[tf][sf] = __builtin_amdgcn_mfma_f32_16x16x32_bf16(kf0, qF[tf][0], st[tf][sf], 0,0,0);
            st[tf][sf] = __builtin_amdgcn_mfma_f32_16x16x32_bf16(kf1, qF[tf][1], st[tf][sf], 0,0,0);
          }
        }
        if (kbase + 63 > trow0){  // causal mask on near-diagonal tiles
          #pragma unroll
          for (int tf = 0; tf < 2; tf++){
            int tg = trow0 + tf*16 + tl;
            #pragma unroll
            for (int sf = 0; sf < 4; sf++)
              #pragma unroll
              for (int r = 0; r < 4; r++)
                if (kbase + sf*16 + g*4 + r > tg) st[tf][sf][r] = -1e30f;
          }
        }
        #pragma unroll
        for (int tf = 0; tf < 2; tf++){
          float mloc = -1e30f;
          #pragma unroll
          for (int sf = 0; sf < 4; sf++)
            #pragma unroll
            for (int r = 0; r < 4; r++) mloc = fmaxf(mloc, st[tf][sf][r]);
          mloc = fmaxf(mloc, __shfl_xor(mloc, 16));
          mloc = fmaxf(mloc, __shfl_xor(mloc, 32));
          if (__any(mloc > mreg[tf] + 8.f)){   // T13 defer-max
            float mnew = fmaxf(mreg[tf], mloc);
            float alpha = exp2fast(mreg[tf] - mnew);
            mreg[tf] = mnew;
            lreg[tf] *= alpha;
            #pragma unroll
            for (int df = 0; df < 4; df++)
              #pragma unroll
              for (int r = 0; r < 4; r++) acc[tf][df][r] *= alpha;
          }
          float sum = 0.f;
          #pragma unroll
          for (int sf = 0; sf < 4; sf++){
            ushort4e pk;
            #pragma unroll
            for (int r = 0; r < 4; r++){
              float p = exp2fast(st[tf][sf][r] - mreg[tf]);
              sum += p;
              pk[r] = f2b(p);
            }
            *(ushort4e*)&pl[w][tf*16 + tl][sf*16 + g*4] = pk;
          }
          sum += __shfl_xor(sum, 16);
          sum += __shfl_xor(sum, 32);
          lreg[tf] += sum;
        }
        // P^T as B-operand; V^T as A-operand
        bf16x8 pa[2][2];
        #pragma unroll
        for (int tf = 0; tf < 2; tf++)
          #pragma unroll
          for (int ks = 0; ks < 2; ks++)
            pa[tf][ks] = as_bf(*(const ushort8*)&pl[w][tf*16 + tl][ks*32 + g*8]);
        #pragma unroll
        for (int df = 0; df < 4; df++){
          const int row = df*16 + tl;
          bf16x8 vf0 = as_bf(*(const ushort8*)&vcur[row*64 + ((g     ^ s7)*8)]);
          bf16x8 vf1 = as_bf(*(const ushort8*)&vcur[row*64 + (((4+g) ^ s7)*8)]);
          #pragma unroll
          for (int tf = 0; tf < 2; tf++){
            acc[tf][df] = __builtin_amdgcn_mfma_f32_16x16x32_bf16(vf0, pa[tf][0], acc[tf][df], 0,0,0);
            acc[tf][df] = __builtin_amdgcn_mfma_f32_16x16x32_bf16(vf1, pa[tf][1], acc[tf][df], 0,0,0);
          }
        }
      }
      __syncthreads();
    }
    #pragma unroll
    for (int tf = 0; tf < 2; tf++){
      float inv = 1.f / lreg[tf];
      int tg = trow0 + tf*16 + tl;
      #pragma unroll
      for (int df = 0; df < 4; df++){
        ushort4e ov;
        #pragma unroll
        for (int r = 0; r < 4; r++) ov[r] = f2b(acc[tf][df][r] * inv);
        *(ushort4e*)&o[((size_t)(b*T_SEQ + tg))*C_DIM + h*DHD + df*16 + g*4] = ov;
      }
    }
  }
}

// ---------------- GEMM: output projection + bias ----------------
__global__ __launch_bounds__(256) void k_gemm_proj(const unsigned short* __restrict__ ab,
                                                   const unsigned short* __restrict__ wot,
                                                   const float* __restrict__ bo,
                                                   float* __restrict__ out){
  __shared__ __align__(16) unsigned short a_lds[128*64];
  __shared__ __align__(16) unsigned short b_lds[128*64];
  const int tid = threadIdx.x, lane = tid & 63, wid = tid >> 6;
  const int g = lane >> 4, tl = lane & 15;
  const int wr = wid >> 1, wc = wid & 1;
  const int mbase = blockIdx.y * 128, nbase = blockIdx.x * 128;
  f32x4 acc[4][4] = {};
  for (int kk = 0; kk < C_DIM; kk += 64){
    __syncthreads();
    #pragma unroll
    for (int i = 0; i < 4; i++){
      const int brow = (wid*4 + i)*8;
      const int row  = brow + (lane >> 3);
      const int jj   = (lane & 7) ^ (row & 7);
      gload16(&ab[(size_t)(mbase+row)*C_DIM + kk + jj*8],  &a_lds[brow*64]);
      gload16(&wot[(size_t)(nbase+row)*C_DIM + kk + jj*8], &b_lds[brow*64]);
    }
    __syncthreads();
    bf16x8 aF[4][2], bF[4][2];
    #pragma unroll
    for (int mb = 0; mb < 4; mb++){
      const int row = wr*64 + mb*16 + tl; const int s7 = row & 7;
      aF[mb][0] = as_bf(*(const ushort8*)&a_lds[row*64 + ((g     ^ s7)*8)]);
      aF[mb][1] = as_bf(*(const ushort8*)&a_lds[row*64 + (((4+g) ^ s7)*8)]);
    }
    #pragma unroll
    for (int nb = 0; nb < 4; nb++){
      const int row = wc*64 + nb*16 + tl; const int s7 = row & 7;
      bF[nb][0] = as_bf(*(const ushort8*)&b_lds[row*64 + ((g     ^ s7)*8)]);
      bF[nb][1] = as_bf(*(const ushort8*)&b_lds[row*64 + (((4+g) ^ s7)*8)]);
    }
    #pragma unroll
    for (int mb = 0; mb < 4; mb++)
      #pragma unroll
      for (int nb = 0; nb < 4; nb++){
        acc[mb][nb] = __builtin_amdgcn_mfma_f32_16x16x32_bf16(aF[mb][0], bF[nb][0], acc[mb][nb], 0,0,0);
        acc[mb][nb] = __builtin_amdgcn_mfma_f32_16x16x32_bf16(aF[mb][1], bF[nb][1], acc[mb][nb], 0,0,0);
      }
  }
  #pragma unroll
  for (int mb = 0; mb < 4; mb++){
    #pragma unroll
    for (int nb = 0; nb < 4; nb++){
      #pragma unroll
      for (int r = 0; r < 4; r++){
        int gr = mbase + wr*64 + mb*16 + g*4 + r;
        int gc = nbase + wc*64 + nb*16 + tl;
        out[(size_t)gr*C_DIM + gc] = acc[mb][nb][r] + bo[gc];
      }
    }
  }
}

extern "C" void kernel_launch(void* const* d_in, const int* in_sizes, int n_in,
                              void* d_out, int out_size, void* d_ws, size_t ws_size,
                              hipStream_t stream){
  const float* x  = (const float*)d_in[0];
  const float* Wq = (const float*)d_in[1];
  const float* Wk = (const float*)d_in[2];
  const float* Wv = (const float*)d_in[3];
  const float* Wo = (const float*)d_in[4];
  const float* bo = (const float*)d_in[5];
  float* out = (float*)d_out;

  char* p = (char*)d_ws;
  unsigned short* xb  = (unsigned short*)p; p += (size_t)M_ROWS*C_DIM*2;   // 16MB
  unsigned short* wt  = (unsigned short*)p; p += (size_t)3*C_DIM*C_DIM*2;  // 6MB
  unsigned short* wot = (unsigned short*)p; p += (size_t)C_DIM*C_DIM*2;    // 2MB
  unsigned short* Qb  = (unsigned short*)p; p += (size_t)M_ROWS*C_DIM*2;   // 16MB
  unsigned short* Kb  = (unsigned short*)p; p += (size_t)M_ROWS*C_DIM*2;   // 16MB
  unsigned short* Vb  = (unsigned short*)p; p += (size_t)M_ROWS*C_DIM*2;   // 16MB
  unsigned short* Vtr  = xb;   // reuse: xb dead after k_gemm_qkv
  unsigned short* attn = Vb;   // reuse: Vb dead after k_tr_v

  hipLaunchKernelGGL(k_conv_x, dim3(M_ROWS*C_DIM/4/256), dim3(256), 0, stream, x, xb);
  hipLaunchKernelGGL(k_pack_w, dim3(4*C_DIM*C_DIM/256), dim3(256), 0, stream,
                     Wq, Wk, Wv, Wo, wt, wot);
  hipLaunchKernelGGL(k_gemm_qkv, dim3(3*C_DIM/128, M_ROWS/128), dim3(256), 0, stream,
                     xb, wt, Qb, Kb, Vb);
  hipLaunchKernelGGL(k_tr_v, dim3(T_SEQ/64, B_NUM*H_NUM), dim3(256), 0, stream, Vb, Vtr);
  hipLaunchKernelGGL(k_flash, dim3(8, B_NUM*H_NUM), dim3(256), 0, stream,
                     Qb, Kb, Vtr, attn);
  hipLaunchKernelGGL(k_gemm_proj, dim3(C_DIM/128, M_ROWS/128), dim3(256), 0, stream,
                     attn, wot, bo, out);
}

// Round 6
// 191.231 us; speedup vs baseline: 2.2877x; 1.0558x over previous
//
#include <hip/hip_runtime.h>

// MHA fused forward: B=4, T=2048, C=1024, H=16, DH=64
#define T_SEQ 2048
#define C_DIM 1024
#define H_NUM 16
#define DHD   64
#define B_NUM 4
#define M_ROWS (B_NUM*T_SEQ)   // 8192

typedef __bf16 bf16x8 __attribute__((ext_vector_type(8)));
typedef float  f32x4  __attribute__((ext_vector_type(4)));
typedef unsigned short ushort8 __attribute__((ext_vector_type(8)));
typedef unsigned short ushort4e __attribute__((ext_vector_type(4)));

__device__ __forceinline__ unsigned short f2b(float f){
  return __builtin_bit_cast(unsigned short, (__bf16)f);
}
__device__ __forceinline__ bf16x8 as_bf(ushort8 u){ return __builtin_bit_cast(bf16x8, u); }
__device__ __forceinline__ float exp2fast(float x){ return __builtin_amdgcn_exp2f(x); }

__device__ __forceinline__ void gload16(const void* g, void* l){
  __builtin_amdgcn_global_load_lds(
      (const __attribute__((address_space(1))) void*)g,
      (__attribute__((address_space(3))) void*)l, 16, 0, 0);
}

// ---------------- convert x (f32 -> bf16) ----------------
__global__ __launch_bounds__(256) void k_conv_x(const float* __restrict__ x,
                                                unsigned short* __restrict__ xb){
  int i = blockIdx.x*256 + threadIdx.x;
  float4 f = ((const float4*)x)[i];
  ushort4e o;
  o[0]=f2b(f.x); o[1]=f2b(f.y); o[2]=f2b(f.z); o[3]=f2b(f.w);
  ((ushort4e*)xb)[i] = o;
}

// ---------------- pack weights ----------------
// wt: (3*C, C) bf16 rows n=(m,h,d), cols c. Wq rows scaled by 0.125*log2(e)
// (softmax computed in exp2 domain). wot: (C,C) wot[n][c] = Wo[c][n].
__global__ __launch_bounds__(256) void k_pack_w(const float* __restrict__ wq,
                                                const float* __restrict__ wk,
                                                const float* __restrict__ wv,
                                                const float* __restrict__ wo,
                                                unsigned short* __restrict__ wt,
                                                unsigned short* __restrict__ wot){
  int idx = blockIdx.x*256 + threadIdx.x;
  if (idx < 3*C_DIM*C_DIM){
    int nall = idx >> 10; int c = idx & 1023;
    int m = nall >> 10;   int n = nall & 1023;
    int h = n >> 6, d = n & 63;
    const float* w = (m==0) ? wq : (m==1) ? wk : wv;
    float f = w[((size_t)h*C_DIM + c)*DHD + d];
    if (m == 0) f *= 0.125f * 1.4426950408889634f;  // DH^-0.5 * log2(e)
    wt[idx] = f2b(f);
  } else {
    int j = idx - 3*C_DIM*C_DIM;
    int n = j >> 10, c = j & 1023;
    wot[j] = f2b(wo[(size_t)c*C_DIM + n]);
  }
}

// ---------------- GEMM (m97-structure): BK=64, global_load_lds, XOR swizzle ----------------
// C[m][n] = sum_k A[m][k]*Bt[n][k].  1D grid, XCD-aware bijective swizzle.
__global__ __launch_bounds__(256) void k_gemm_qkv(const unsigned short* __restrict__ xb,
                                                  const unsigned short* __restrict__ wt,
                                                  unsigned short* __restrict__ qo,
                                                  unsigned short* __restrict__ ko,
                                                  unsigned short* __restrict__ vo){
  __shared__ __align__(16) unsigned short a_lds[128*64];
  __shared__ __align__(16) unsigned short b_lds[128*64];
  const int tid = threadIdx.x, lane = tid & 63, wid = tid >> 6;
  const int g = lane >> 4, tl = lane & 15;
  const int wr = wid >> 1, wc = wid & 1;
  // XCD swizzle: 1536 blocks, 192 per XCD, contiguous logical range per XCD
  const int id = blockIdx.x;
  const int swz = (id & 7)*192 + (id >> 3);
  const int mbase = (swz / 24) * 128, nbase = (swz % 24) * 128;
  f32x4 acc[4][4] = {};
  for (int kk = 0; kk < C_DIM; kk += 64){
    __syncthreads();
    #pragma unroll
    for (int i = 0; i < 4; i++){
      const int brow = (wid*4 + i)*8;
      const int row  = brow + (lane >> 3);
      const int jj   = (lane & 7) ^ (row & 7);
      gload16(&xb[(size_t)(mbase+row)*C_DIM + kk + jj*8], &a_lds[brow*64]);
      gload16(&wt[(size_t)(nbase+row)*C_DIM + kk + jj*8], &b_lds[brow*64]);
    }
    __syncthreads();
    bf16x8 aF[4][2], bF[4][2];
    #pragma unroll
    for (int mb = 0; mb < 4; mb++){
      const int row = wr*64 + mb*16 + tl; const int s7 = row & 7;
      aF[mb][0] = as_bf(*(const ushort8*)&a_lds[row*64 + ((g     ^ s7)*8)]);
      aF[mb][1] = as_bf(*(const ushort8*)&a_lds[row*64 + (((4+g) ^ s7)*8)]);
    }
    #pragma unroll
    for (int nb = 0; nb < 4; nb++){
      const int row = wc*64 + nb*16 + tl; const int s7 = row & 7;
      bF[nb][0] = as_bf(*(const ushort8*)&b_lds[row*64 + ((g     ^ s7)*8)]);
      bF[nb][1] = as_bf(*(const ushort8*)&b_lds[row*64 + (((4+g) ^ s7)*8)]);
    }
    #pragma unroll
    for (int mb = 0; mb < 4; mb++)
      #pragma unroll
      for (int nb = 0; nb < 4; nb++){
        acc[mb][nb] = __builtin_amdgcn_mfma_f32_16x16x32_bf16(aF[mb][0], bF[nb][0], acc[mb][nb], 0,0,0);
        acc[mb][nb] = __builtin_amdgcn_mfma_f32_16x16x32_bf16(aF[mb][1], bF[nb][1], acc[mb][nb], 0,0,0);
      }
  }
  #pragma unroll
  for (int mb = 0; mb < 4; mb++){
    #pragma unroll
    for (int nb = 0; nb < 4; nb++){
      #pragma unroll
      for (int r = 0; r < 4; r++){
        int gr = mbase + wr*64 + mb*16 + g*4 + r;
        int gc = nbase + wc*64 + nb*16 + tl;
        int b = gr >> 11, t = gr & 2047;
        int sel = gc >> 10, nw = gc & 1023;
        int h = nw >> 6, d = nw & 63;
        unsigned short* dst = (sel == 0) ? qo : (sel == 1) ? ko : vo;
        dst[(((size_t)(b*H_NUM + h))*T_SEQ + t)*DHD + d] = f2b(acc[mb][nb][r]);
      }
    }
  }
}

// ---------------- V transpose: (bh, t, d) -> (bh, d, t) ----------------
__global__ __launch_bounds__(256) void k_tr_v(const unsigned short* __restrict__ vsrc,
                                              unsigned short* __restrict__ vdst){
  __shared__ __align__(16) unsigned short vr[64][72];
  int tid = threadIdx.x;
  int bh = blockIdx.y; int tbase = blockIdx.x * 64;
  const unsigned short* vb = vsrc + (size_t)bh * T_SEQ * DHD;
  unsigned short* vo = vdst + (size_t)bh * DHD * T_SEQ;
  #pragma unroll
  for (int i = 0; i < 2; i++){
    int id = tid + i*256;
    int row = id >> 3, c8 = (id & 7) << 3;
    *(ushort8*)&vr[row][c8 ^ ((row >> 3) << 3)] =
        *(const ushort8*)&vb[(size_t)(tbase + row)*DHD + c8];
  }
  __syncthreads();
  #pragma unroll
  for (int i = 0; i < 2; i++){
    int id = tid + i*256;
    int d = id >> 3, oc = id & 7;
    ushort8 out;
    #pragma unroll
    for (int j = 0; j < 8; j++){
      int t = oc*8 + j;
      out[j] = vr[t][d ^ (oc << 3)];
    }
    *(ushort8*)&vo[(size_t)d*T_SEQ + tbase + oc*8] = out;
  }
}

// ---------------- Flash attention (causal): 8-wave blocks, QBLK=256 ----------------
// grid: 256 blocks (1/CU). Block handles Q-super-tile pair {bx, 7-bx} (36 tile-iters).
// 8 waves x 32 Q-rows; KVBLK=64 double-buffered via global_load_lds (pre-swizzled src);
// exp2-domain softmax + defer-max + setprio around MFMA.
__global__ __launch_bounds__(512) void k_flash(const unsigned short* __restrict__ q,
                                               const unsigned short* __restrict__ k,
                                               const unsigned short* __restrict__ vtg,
                                               unsigned short* __restrict__ o){
  __shared__ __align__(16) unsigned short kbufs[2][64*64];
  __shared__ __align__(16) unsigned short vbufs[2][64*64];
  __shared__ __align__(16) unsigned short pl[8][32][72];   // P rows are 64 cols + 8 pad
  const int tid = threadIdx.x, lane = tid & 63, w = tid >> 6;
  const int g = lane >> 4, tl = lane & 15;
  // XCD swizzle: 256 blocks -> contiguous bh range per XCD (K/V L2 reuse)
  const int id = blockIdx.x;
  const int swz = (id & 7)*32 + (id >> 3);
  const int bh = swz >> 2, bx = swz & 3;
  const int b = bh >> 4, h = bh & 15;
  const unsigned short* qb = q   + (size_t)bh * T_SEQ * DHD;
  const unsigned short* kb = k   + (size_t)bh * T_SEQ * DHD;
  const unsigned short* vb = vtg + (size_t)bh * (size_t)DHD * T_SEQ;
  const int lrow = lane >> 3, lj = lane & 7;

  for (int pass = 0; pass < 2; ++pass){
    const int qt = pass ? (7 - bx) : bx;
    const int tbase = qt * 256;
    const int trow0 = tbase + w * 32;
    const int tmax = trow0 + 31;
    bf16x8 qF[2][2];
    #pragma unroll
    for (int tf = 0; tf < 2; tf++)
      #pragma unroll
      for (int ks = 0; ks < 2; ks++)
        qF[tf][ks] = as_bf(*(const ushort8*)&qb[(size_t)(trow0 + tf*16 + tl)*DHD + ks*32 + g*8]);
    f32x4 acc[2][4] = {};
    float mreg[2] = {-1e30f, -1e30f}, lreg[2] = {0.f, 0.f};
    const int nkt = 4*qt + 4;
    // prologue: stage tile 0 into buf 0 (each wave stages 8 rows of K and V^T)
    {
      const int row = w*8 + lrow;
      const int jj = lj ^ (row & 7);
      gload16(&kb[(size_t)row*DHD + jj*8],   &kbufs[0][w*8*64]);
      gload16(&vb[(size_t)row*T_SEQ + jj*8], &vbufs[0][w*8*64]);
    }
    __syncthreads();
    for (int kti = 0; kti < nkt; ++kti){
      const int cur = kti & 1;
      const int kbase = kti * 64;
      if (kti + 1 < nkt){
        const int kb2 = kbase + 64;
        const int row = w*8 + lrow;
        const int jj = lj ^ (row & 7);
        gload16(&kb[(size_t)(kb2+row)*DHD + jj*8],   &kbufs[cur^1][w*8*64]);
        gload16(&vb[(size_t)row*T_SEQ + kb2 + jj*8], &vbufs[cur^1][w*8*64]);
      }
      if (kbase <= tmax){
        const unsigned short* kcur = kbufs[cur];
        const unsigned short* vcur = vbufs[cur];
        const int s7 = tl & 7;
        f32x4 st[2][4] = {};
        __builtin_amdgcn_s_setprio(1);
        #pragma unroll
        for (int sf = 0; sf < 4; sf++){
          const int row = sf*16 + tl;
          bf16x8 kf0 = as_bf(*(const ushort8*)&kcur[row*64 + ((g     ^ s7)*8)]);
          bf16x8 kf1 = as_bf(*(const ushort8*)&kcur[row*64 + (((4+g) ^ s7)*8)]);
          #pragma unroll
          for (int tf = 0; tf < 2; tf++){
            st[tf][sf] = __builtin_amdgcn_mfma_f32_16x16x32_bf16(kf0, qF[tf][0], st[tf][sf], 0,0,0);
            st[tf][sf] = __builtin_amdgcn_mfma_f32_16x16x32_bf16(kf1, qF[tf][1], st[tf][sf], 0,0,0);
          }
        }
        __builtin_amdgcn_s_setprio(0);
        if (kbase + 63 > trow0){  // causal mask on near-diagonal tiles
          #pragma unroll
          for (int tf = 0; tf < 2; tf++){
            int tg = trow0 + tf*16 + tl;
            #pragma unroll
            for (int sf = 0; sf < 4; sf++)
              #pragma unroll
              for (int r = 0; r < 4; r++)
                if (kbase + sf*16 + g*4 + r > tg) st[tf][sf][r] = -1e30f;
          }
        }
        #pragma unroll
        for (int tf = 0; tf < 2; tf++){
          float mloc = -1e30f;
          #pragma unroll
          for (int sf = 0; sf < 4; sf++)
            #pragma unroll
            for (int r = 0; r < 4; r++) mloc = fmaxf(mloc, st[tf][sf][r]);
          mloc = fmaxf(mloc, __shfl_xor(mloc, 16));
          mloc = fmaxf(mloc, __shfl_xor(mloc, 32));
          if (__any(mloc > mreg[tf] + 8.f)){   // T13 defer-max
            float mnew = fmaxf(mreg[tf], mloc);
            float alpha = exp2fast(mreg[tf] - mnew);
            mreg[tf] = mnew;
            lreg[tf] *= alpha;
            #pragma unroll
            for (int df = 0; df < 4; df++)
              #pragma unroll
              for (int r = 0; r < 4; r++) acc[tf][df][r] *= alpha;
          }
          float sum = 0.f;
          #pragma unroll
          for (int sf = 0; sf < 4; sf++){
            ushort4e pk;
            #pragma unroll
            for (int r = 0; r < 4; r++){
              float p = exp2fast(st[tf][sf][r] - mreg[tf]);
              sum += p;
              pk[r] = f2b(p);
            }
            *(ushort4e*)&pl[w][tf*16 + tl][sf*16 + g*4] = pk;
          }
          sum += __shfl_xor(sum, 16);
          sum += __shfl_xor(sum, 32);
          lreg[tf] += sum;
        }
        // P^T as B-operand; V^T as A-operand
        bf16x8 pa[2][2];
        #pragma unroll
        for (int tf = 0; tf < 2; tf++)
          #pragma unroll
          for (int ks = 0; ks < 2; ks++)
            pa[tf][ks] = as_bf(*(const ushort8*)&pl[w][tf*16 + tl][ks*32 + g*8]);
        __builtin_amdgcn_s_setprio(1);
        #pragma unroll
        for (int df = 0; df < 4; df++){
          const int row = df*16 + tl;
          bf16x8 vf0 = as_bf(*(const ushort8*)&vcur[row*64 + ((g     ^ s7)*8)]);
          bf16x8 vf1 = as_bf(*(const ushort8*)&vcur[row*64 + (((4+g) ^ s7)*8)]);
          #pragma unroll
          for (int tf = 0; tf < 2; tf++){
            acc[tf][df] = __builtin_amdgcn_mfma_f32_16x16x32_bf16(vf0, pa[tf][0], acc[tf][df], 0,0,0);
            acc[tf][df] = __builtin_amdgcn_mfma_f32_16x16x32_bf16(vf1, pa[tf][1], acc[tf][df], 0,0,0);
          }
        }
        __builtin_amdgcn_s_setprio(0);
      }
      __syncthreads();
    }
    #pragma unroll
    for (int tf = 0; tf < 2; tf++){
      float inv = 1.f / lreg[tf];
      int tg = trow0 + tf*16 + tl;
      #pragma unroll
      for (int df = 0; df < 4; df++){
        ushort4e ov;
        #pragma unroll
        for (int r = 0; r < 4; r++) ov[r] = f2b(acc[tf][df][r] * inv);
        *(ushort4e*)&o[((size_t)(b*T_SEQ + tg))*C_DIM + h*DHD + df*16 + g*4] = ov;
      }
    }
  }
}

// ---------------- GEMM: output projection + bias ----------------
__global__ __launch_bounds__(256) void k_gemm_proj(const unsigned short* __restrict__ ab,
                                                   const unsigned short* __restrict__ wot,
                                                   const float* __restrict__ bo,
                                                   float* __restrict__ out){
  __shared__ __align__(16) unsigned short a_lds[128*64];
  __shared__ __align__(16) unsigned short b_lds[128*64];
  const int tid = threadIdx.x, lane = tid & 63, wid = tid >> 6;
  const int g = lane >> 4, tl = lane & 15;
  const int wr = wid >> 1, wc = wid & 1;
  // XCD swizzle: 512 blocks, 64 per XCD
  const int id = blockIdx.x;
  const int swz = (id & 7)*64 + (id >> 3);
  const int mbase = (swz >> 3) * 128, nbase = (swz & 7) * 128;
  f32x4 acc[4][4] = {};
  for (int kk = 0; kk < C_DIM; kk += 64){
    __syncthreads();
    #pragma unroll
    for (int i = 0; i < 4; i++){
      const int brow = (wid*4 + i)*8;
      const int row  = brow + (lane >> 3);
      const int jj   = (lane & 7) ^ (row & 7);
      gload16(&ab[(size_t)(mbase+row)*C_DIM + kk + jj*8],  &a_lds[brow*64]);
      gload16(&wot[(size_t)(nbase+row)*C_DIM + kk + jj*8], &b_lds[brow*64]);
    }
    __syncthreads();
    bf16x8 aF[4][2], bF[4][2];
    #pragma unroll
    for (int mb = 0; mb < 4; mb++){
      const int row = wr*64 + mb*16 + tl; const int s7 = row & 7;
      aF[mb][0] = as_bf(*(const ushort8*)&a_lds[row*64 + ((g     ^ s7)*8)]);
      aF[mb][1] = as_bf(*(const ushort8*)&a_lds[row*64 + (((4+g) ^ s7)*8)]);
    }
    #pragma unroll
    for (int nb = 0; nb < 4; nb++){
      const int row = wc*64 + nb*16 + tl; const int s7 = row & 7;
      bF[nb][0] = as_bf(*(const ushort8*)&b_lds[row*64 + ((g     ^ s7)*8)]);
      bF[nb][1] = as_bf(*(const ushort8*)&b_lds[row*64 + (((4+g) ^ s7)*8)]);
    }
    #pragma unroll
    for (int mb = 0; mb < 4; mb++)
      #pragma unroll
      for (int nb = 0; nb < 4; nb++){
        acc[mb][nb] = __builtin_amdgcn_mfma_f32_16x16x32_bf16(aF[mb][0], bF[nb][0], acc[mb][nb], 0,0,0);
        acc[mb][nb] = __builtin_amdgcn_mfma_f32_16x16x32_bf16(aF[mb][1], bF[nb][1], acc[mb][nb], 0,0,0);
      }
  }
  #pragma unroll
  for (int mb = 0; mb < 4; mb++){
    #pragma unroll
    for (int nb = 0; nb < 4; nb++){
      #pragma unroll
      for (int r = 0; r < 4; r++){
        int gr = mbase + wr*64 + mb*16 + g*4 + r;
        int gc = nbase + wc*64 + nb*16 + tl;
        out[(size_t)gr*C_DIM + gc] = acc[mb][nb][r] + bo[gc];
      }
    }
  }
}

extern "C" void kernel_launch(void* const* d_in, const int* in_sizes, int n_in,
                              void* d_out, int out_size, void* d_ws, size_t ws_size,
                              hipStream_t stream){
  const float* x  = (const float*)d_in[0];
  const float* Wq = (const float*)d_in[1];
  const float* Wk = (const float*)d_in[2];
  const float* Wv = (const float*)d_in[3];
  const float* Wo = (const float*)d_in[4];
  const float* bo = (const float*)d_in[5];
  float* out = (float*)d_out;

  char* p = (char*)d_ws;
  unsigned short* xb  = (unsigned short*)p; p += (size_t)M_ROWS*C_DIM*2;   // 16MB
  unsigned short* wt  = (unsigned short*)p; p += (size_t)3*C_DIM*C_DIM*2;  // 6MB
  unsigned short* wot = (unsigned short*)p; p += (size_t)C_DIM*C_DIM*2;    // 2MB
  unsigned short* Qb  = (unsigned short*)p; p += (size_t)M_ROWS*C_DIM*2;   // 16MB
  unsigned short* Kb  = (unsigned short*)p; p += (size_t)M_ROWS*C_DIM*2;   // 16MB
  unsigned short* Vb  = (unsigned short*)p; p += (size_t)M_ROWS*C_DIM*2;   // 16MB
  unsigned short* Vtr  = xb;   // reuse: xb dead after k_gemm_qkv
  unsigned short* attn = Vb;   // reuse: Vb dead after k_tr_v

  hipLaunchKernelGGL(k_conv_x, dim3(M_ROWS*C_DIM/4/256), dim3(256), 0, stream, x, xb);
  hipLaunchKernelGGL(k_pack_w, dim3(4*C_DIM*C_DIM/256), dim3(256), 0, stream,
                     Wq, Wk, Wv, Wo, wt, wot);
  hipLaunchKernelGGL(k_gemm_qkv, dim3(1536), dim3(256), 0, stream,
                     xb, wt, Qb, Kb, Vb);
  hipLaunchKernelGGL(k_tr_v, dim3(T_SEQ/64, B_NUM*H_NUM), dim3(256), 0, stream, Vb, Vtr);
  hipLaunchKernelGGL(k_flash, dim3(256), dim3(512), 0, stream,
                     Qb, Kb, Vtr, attn);
  hipLaunchKernelGGL(k_gemm_proj, dim3(512), dim3(256), 0, stream,
                     attn, wot, bo, out);
}

// Round 7
// 183.296 us; speedup vs baseline: 2.3867x; 1.0433x over previous
//
#include <hip/hip_runtime.h>

// MHA fused forward: B=4, T=2048, C=1024, H=16, DH=64
#define T_SEQ 2048
#define C_DIM 1024
#define H_NUM 16
#define DHD   64
#define B_NUM 4
#define M_ROWS (B_NUM*T_SEQ)   // 8192

typedef __bf16 bf16x8 __attribute__((ext_vector_type(8)));
typedef float  f32x4  __attribute__((ext_vector_type(4)));
typedef unsigned short ushort8 __attribute__((ext_vector_type(8)));
typedef unsigned short ushort4e __attribute__((ext_vector_type(4)));

__device__ __forceinline__ unsigned short f2b(float f){
  return __builtin_bit_cast(unsigned short, (__bf16)f);
}
__device__ __forceinline__ bf16x8 as_bf(ushort8 u){ return __builtin_bit_cast(bf16x8, u); }
__device__ __forceinline__ float exp2fast(float x){ return __builtin_amdgcn_exp2f(x); }

__device__ __forceinline__ void gload16(const void* g, void* l){
  __builtin_amdgcn_global_load_lds(
      (const __attribute__((address_space(1))) void*)g,
      (__attribute__((address_space(3))) void*)l, 16, 0, 0);
}

// ---------------- convert x (f32 -> bf16) ----------------
__global__ __launch_bounds__(256) void k_conv_x(const float* __restrict__ x,
                                                unsigned short* __restrict__ xb){
  int i = blockIdx.x*256 + threadIdx.x;
  float4 f = ((const float4*)x)[i];
  ushort4e o;
  o[0]=f2b(f.x); o[1]=f2b(f.y); o[2]=f2b(f.z); o[3]=f2b(f.w);
  ((ushort4e*)xb)[i] = o;
}

// ---------------- pack weights ----------------
// wt: (3*C, C) bf16 rows n=(m,h,d), cols c. Wq rows scaled by 0.125*log2(e)
// (softmax computed in exp2 domain). wot: (C,C) wot[n][c] = Wo[c][n].
__global__ __launch_bounds__(256) void k_pack_w(const float* __restrict__ wq,
                                                const float* __restrict__ wk,
                                                const float* __restrict__ wv,
                                                const float* __restrict__ wo,
                                                unsigned short* __restrict__ wt,
                                                unsigned short* __restrict__ wot){
  int idx = blockIdx.x*256 + threadIdx.x;
  if (idx < 3*C_DIM*C_DIM){
    int nall = idx >> 10; int c = idx & 1023;
    int m = nall >> 10;   int n = nall & 1023;
    int h = n >> 6, d = n & 63;
    const float* w = (m==0) ? wq : (m==1) ? wk : wv;
    float f = w[((size_t)h*C_DIM + c)*DHD + d];
    if (m == 0) f *= 0.125f * 1.4426950408889634f;  // DH^-0.5 * log2(e)
    wt[idx] = f2b(f);
  } else {
    int j = idx - 3*C_DIM*C_DIM;
    int n = j >> 10, c = j & 1023;
    wot[j] = f2b(wo[(size_t)c*C_DIM + n]);
  }
}

// ---------------- GEMM: QKV projection (m97 structure) ----------------
// C[m][n] = sum_k A[m][k]*Bt[n][k]. sel==2 (V) blocks write V^T via LDS transpose.
__global__ __launch_bounds__(256) void k_gemm_qkv(const unsigned short* __restrict__ xb,
                                                  const unsigned short* __restrict__ wt,
                                                  unsigned short* __restrict__ qo,
                                                  unsigned short* __restrict__ ko,
                                                  unsigned short* __restrict__ vtr){
  __shared__ __align__(16) unsigned short smem[2][128*64];
  const int tid = threadIdx.x, lane = tid & 63, wid = tid >> 6;
  const int g = lane >> 4, tl = lane & 15;
  const int wr = wid >> 1, wc = wid & 1;
  // XCD swizzle: 1536 blocks, 192 per XCD, contiguous logical range per XCD
  const int id = blockIdx.x;
  const int swz = (id & 7)*192 + (id >> 3);
  const int mbase = (swz / 24) * 128, nbase = (swz % 24) * 128;
  f32x4 acc[4][4] = {};
  for (int kk = 0; kk < C_DIM; kk += 64){
    __syncthreads();
    #pragma unroll
    for (int i = 0; i < 4; i++){
      const int brow = (wid*4 + i)*8;
      const int row  = brow + (lane >> 3);
      const int jj   = (lane & 7) ^ (row & 7);
      gload16(&xb[(size_t)(mbase+row)*C_DIM + kk + jj*8], &smem[0][brow*64]);
      gload16(&wt[(size_t)(nbase+row)*C_DIM + kk + jj*8], &smem[1][brow*64]);
    }
    __syncthreads();
    bf16x8 aF[4][2], bF[4][2];
    #pragma unroll
    for (int mb = 0; mb < 4; mb++){
      const int row = wr*64 + mb*16 + tl; const int s7 = row & 7;
      aF[mb][0] = as_bf(*(const ushort8*)&smem[0][row*64 + ((g     ^ s7)*8)]);
      aF[mb][1] = as_bf(*(const ushort8*)&smem[0][row*64 + (((4+g) ^ s7)*8)]);
    }
    #pragma unroll
    for (int nb = 0; nb < 4; nb++){
      const int row = wc*64 + nb*16 + tl; const int s7 = row & 7;
      bF[nb][0] = as_bf(*(const ushort8*)&smem[1][row*64 + ((g     ^ s7)*8)]);
      bF[nb][1] = as_bf(*(const ushort8*)&smem[1][row*64 + (((4+g) ^ s7)*8)]);
    }
    #pragma unroll
    for (int mb = 0; mb < 4; mb++)
      #pragma unroll
      for (int nb = 0; nb < 4; nb++){
        acc[mb][nb] = __builtin_amdgcn_mfma_f32_16x16x32_bf16(aF[mb][0], bF[nb][0], acc[mb][nb], 0,0,0);
        acc[mb][nb] = __builtin_amdgcn_mfma_f32_16x16x32_bf16(aF[mb][1], bF[nb][1], acc[mb][nb], 0,0,0);
      }
  }
  const int sel = nbase >> 10;   // block-uniform (128-col tile within one sel)
  if (sel < 2){
    unsigned short* dst0 = (sel == 0) ? qo : ko;
    #pragma unroll
    for (int mb = 0; mb < 4; mb++){
      #pragma unroll
      for (int nb = 0; nb < 4; nb++){
        #pragma unroll
        for (int r = 0; r < 4; r++){
          int gr = mbase + wr*64 + mb*16 + g*4 + r;
          int gc = nbase + wc*64 + nb*16 + tl;
          int b = gr >> 11, t = gr & 2047;
          int nw = gc & 1023;
          int h = nw >> 6, d = nw & 63;
          dst0[(((size_t)(b*H_NUM + h))*T_SEQ + t)*DHD + d] = f2b(acc[mb][nb][r]);
        }
      }
    }
  } else {
    // V block: transpose 128(m)x128(n) tile through swizzled LDS, write V^T[bh][d][t]
    __syncthreads();                       // all waves done reading smem
    unsigned short* tr = &smem[0][0];      // 128*128 ushorts = 32 KB
    #pragma unroll
    for (int mb = 0; mb < 4; mb++){
      #pragma unroll
      for (int nb = 0; nb < 4; nb++){
        const int n = wc*64 + nb*16 + tl;
        const int m0 = wr*64 + mb*16 + g*4;
        ushort4e pk;
        #pragma unroll
        for (int r = 0; r < 4; r++) pk[r] = f2b(acc[mb][nb][r]);
        *(ushort4e*)&tr[n*128 + (m0 ^ ((n & 15) << 3))] = pk;
      }
    }
    __syncthreads();
    const int hbase = (nbase - 2048) >> 6;
    const int b = mbase >> 11, tloc = mbase & 2047;
    const int n = tid >> 1, half = tid & 1;
    unsigned short* vdst = vtr + (((size_t)(b*H_NUM + hbase + (n >> 6)))*DHD + (n & 63))*T_SEQ
                           + tloc + half*64;
    #pragma unroll
    for (int c8 = 0; c8 < 8; c8++){
      const int chunk = (half*8 + c8) ^ (n & 15);
      *(ushort8*)&vdst[c8*8] = *(const ushort8*)&tr[n*128 + chunk*8];
    }
  }
}

// ---------------- Flash attention (causal): 8-wave blocks, QBLK=256 ----------------
// grid: 256 blocks (1/CU). Block handles Q-super-tile pair {bx, 7-bx} (36 tile-iters).
// 8 waves x 32 Q-rows; KVBLK=64 double-buffered via global_load_lds (pre-swizzled src);
// exp2-domain softmax, lazy-max (shfl-free steady state), partial l-sum, setprio.
__global__ __launch_bounds__(512) void k_flash(const unsigned short* __restrict__ q,
                                               const unsigned short* __restrict__ k,
                                               const unsigned short* __restrict__ vtg,
                                               unsigned short* __restrict__ o){
  __shared__ __align__(16) unsigned short kbufs[2][64*64];
  __shared__ __align__(16) unsigned short vbufs[2][64*64];
  __shared__ __align__(16) unsigned short pl[8][32][72];   // P rows are 64 cols + 8 pad
  const int tid = threadIdx.x, lane = tid & 63, w = tid >> 6;
  const int g = lane >> 4, tl = lane & 15;
  // XCD swizzle: 256 blocks -> contiguous bh range per XCD (K/V L2 reuse)
  const int id = blockIdx.x;
  const int swz = (id & 7)*32 + (id >> 3);
  const int bh = swz >> 2, bx = swz & 3;
  const int b = bh >> 4, h = bh & 15;
  const unsigned short* qb = q   + (size_t)bh * T_SEQ * DHD;
  const unsigned short* kb = k   + (size_t)bh * T_SEQ * DHD;
  const unsigned short* vb = vtg + (size_t)bh * (size_t)DHD * T_SEQ;
  const int lrow = lane >> 3, lj = lane & 7;

  for (int pass = 0; pass < 2; ++pass){
    const int qt = pass ? (7 - bx) : bx;
    const int tbase = qt * 256;
    const int trow0 = tbase + w * 32;
    const int tmax = trow0 + 31;
    bf16x8 qF[2][2];
    #pragma unroll
    for (int tf = 0; tf < 2; tf++)
      #pragma unroll
      for (int ks = 0; ks < 2; ks++)
        qF[tf][ks] = as_bf(*(const ushort8*)&qb[(size_t)(trow0 + tf*16 + tl)*DHD + ks*32 + g*8]);
    f32x4 acc[2][4] = {};
    float mreg[2] = {-1e30f, -1e30f}, lreg[2] = {0.f, 0.f};
    const int nkt = 4*qt + 4;
    // prologue: stage tile 0 into buf 0 (each wave stages 8 rows of K and V^T)
    {
      const int row = w*8 + lrow;
      const int jj = lj ^ (row & 7);
      gload16(&kb[(size_t)row*DHD + jj*8],   &kbufs[0][w*8*64]);
      gload16(&vb[(size_t)row*T_SEQ + jj*8], &vbufs[0][w*8*64]);
    }
    __syncthreads();
    for (int kti = 0; kti < nkt; ++kti){
      const int cur = kti & 1;
      const int kbase = kti * 64;
      if (kti + 1 < nkt){
        const int kb2 = kbase + 64;
        const int row = w*8 + lrow;
        const int jj = lj ^ (row & 7);
        gload16(&kb[(size_t)(kb2+row)*DHD + jj*8],   &kbufs[cur^1][w*8*64]);
        gload16(&vb[(size_t)row*T_SEQ + kb2 + jj*8], &vbufs[cur^1][w*8*64]);
      }
      if (kbase <= tmax){
        const unsigned short* kcur = kbufs[cur];
        const unsigned short* vcur = vbufs[cur];
        const int s7 = tl & 7;
        f32x4 st[2][4] = {};
        __builtin_amdgcn_s_setprio(1);
        #pragma unroll
        for (int sf = 0; sf < 4; sf++){
          const int row = sf*16 + tl;
          bf16x8 kf0 = as_bf(*(const ushort8*)&kcur[row*64 + ((g     ^ s7)*8)]);
          bf16x8 kf1 = as_bf(*(const ushort8*)&kcur[row*64 + (((4+g) ^ s7)*8)]);
          #pragma unroll
          for (int tf = 0; tf < 2; tf++){
            st[tf][sf] = __builtin_amdgcn_mfma_f32_16x16x32_bf16(kf0, qF[tf][0], st[tf][sf], 0,0,0);
            st[tf][sf] = __builtin_amdgcn_mfma_f32_16x16x32_bf16(kf1, qF[tf][1], st[tf][sf], 0,0,0);
          }
        }
        __builtin_amdgcn_s_setprio(0);
        if (kbase + 63 > trow0){  // causal mask on near-diagonal tiles
          #pragma unroll
          for (int tf = 0; tf < 2; tf++){
            int tg = trow0 + tf*16 + tl;
            #pragma unroll
            for (int sf = 0; sf < 4; sf++)
              #pragma unroll
              for (int r = 0; r < 4; r++)
                if (kbase + sf*16 + g*4 + r > tg) st[tf][sf][r] = -1e30f;
          }
        }
        #pragma unroll
        for (int tf = 0; tf < 2; tf++){
          // per-lane partial max over this lane's 16 columns of row tl
          float mloc = -1e30f;
          #pragma unroll
          for (int sf = 0; sf < 4; sf++)
            #pragma unroll
            for (int r = 0; r < 4; r++) mloc = fmaxf(mloc, st[tf][sf][r]);
          // lazy-max: trigger is equivalent to full-row test; reduce only on trigger
          if (__any(mloc > mreg[tf] + 8.f)){
            float mrow = fmaxf(mloc, __shfl_xor(mloc, 16));
            mrow = fmaxf(mrow, __shfl_xor(mrow, 32));
            float mnew = fmaxf(mreg[tf], mrow);
            float alpha = exp2fast(mreg[tf] - mnew);
            mreg[tf] = mnew;
            lreg[tf] *= alpha;
            #pragma unroll
            for (int df = 0; df < 4; df++)
              #pragma unroll
              for (int r = 0; r < 4; r++) acc[tf][df][r] *= alpha;
          }
          float sum = 0.f;
          #pragma unroll
          for (int sf = 0; sf < 4; sf++){
            ushort4e pk;
            #pragma unroll
            for (int r = 0; r < 4; r++){
              float p = exp2fast(st[tf][sf][r] - mreg[tf]);
              sum += p;
              pk[r] = f2b(p);
            }
            *(ushort4e*)&pl[w][tf*16 + tl][sf*16 + g*4] = pk;
          }
          lreg[tf] += sum;   // per-lane partial (16 cols); reduced at end of pass
        }
        // P^T as B-operand; V^T as A-operand
        bf16x8 pa[2][2];
        #pragma unroll
        for (int tf = 0; tf < 2; tf++)
          #pragma unroll
          for (int ks = 0; ks < 2; ks++)
            pa[tf][ks] = as_bf(*(const ushort8*)&pl[w][tf*16 + tl][ks*32 + g*8]);
        __builtin_amdgcn_s_setprio(1);
        #pragma unroll
        for (int df = 0; df < 4; df++){
          const int row = df*16 + tl;
          bf16x8 vf0 = as_bf(*(const ushort8*)&vcur[row*64 + ((g     ^ s7)*8)]);
          bf16x8 vf1 = as_bf(*(const ushort8*)&vcur[row*64 + (((4+g) ^ s7)*8)]);
          #pragma unroll
          for (int tf = 0; tf < 2; tf++){
            acc[tf][df] = __builtin_amdgcn_mfma_f32_16x16x32_bf16(vf0, pa[tf][0], acc[tf][df], 0,0,0);
            acc[tf][df] = __builtin_amdgcn_mfma_f32_16x16x32_bf16(vf1, pa[tf][1], acc[tf][df], 0,0,0);
          }
        }
        __builtin_amdgcn_s_setprio(0);
      }
      __syncthreads();
    }
    #pragma unroll
    for (int tf = 0; tf < 2; tf++){
      float l = lreg[tf];
      l += __shfl_xor(l, 16);
      l += __shfl_xor(l, 32);
      float inv = 1.f / l;
      int tg = trow0 + tf*16 + tl;
      #pragma unroll
      for (int df = 0; df < 4; df++){
        ushort4e ov;
        #pragma unroll
        for (int r = 0; r < 4; r++) ov[r] = f2b(acc[tf][df][r] * inv);
        *(ushort4e*)&o[((size_t)(b*T_SEQ + tg))*C_DIM + h*DHD + df*16 + g*4] = ov;
      }
    }
  }
}

// ---------------- GEMM: output projection + bias ----------------
__global__ __launch_bounds__(256) void k_gemm_proj(const unsigned short* __restrict__ ab,
                                                   const unsigned short* __restrict__ wot,
                                                   const float* __restrict__ bo,
                                                   float* __restrict__ out){
  __shared__ __align__(16) unsigned short a_lds[128*64];
  __shared__ __align__(16) unsigned short b_lds[128*64];
  const int tid = threadIdx.x, lane = tid & 63, wid = tid >> 6;
  const int g = lane >> 4, tl = lane & 15;
  const int wr = wid >> 1, wc = wid & 1;
  // XCD swizzle: 512 blocks, 64 per XCD
  const int id = blockIdx.x;
  const int swz = (id & 7)*64 + (id >> 3);
  const int mbase = (swz >> 3) * 128, nbase = (swz & 7) * 128;
  f32x4 acc[4][4] = {};
  for (int kk = 0; kk < C_DIM; kk += 64){
    __syncthreads();
    #pragma unroll
    for (int i = 0; i < 4; i++){
      const int brow = (wid*4 + i)*8;
      const int row  = brow + (lane >> 3);
      const int jj   = (lane & 7) ^ (row & 7);
      gload16(&ab[(size_t)(mbase+row)*C_DIM + kk + jj*8],  &a_lds[brow*64]);
      gload16(&wot[(size_t)(nbase+row)*C_DIM + kk + jj*8], &b_lds[brow*64]);
    }
    __syncthreads();
    bf16x8 aF[4][2], bF[4][2];
    #pragma unroll
    for (int mb = 0; mb < 4; mb++){
      const int row = wr*64 + mb*16 + tl; const int s7 = row & 7;
      aF[mb][0] = as_bf(*(const ushort8*)&a_lds[row*64 + ((g     ^ s7)*8)]);
      aF[mb][1] = as_bf(*(const ushort8*)&a_lds[row*64 + (((4+g) ^ s7)*8)]);
    }
    #pragma unroll
    for (int nb = 0; nb < 4; nb++){
      const int row = wc*64 + nb*16 + tl; const int s7 = row & 7;
      bF[nb][0] = as_bf(*(const ushort8*)&b_lds[row*64 + ((g     ^ s7)*8)]);
      bF[nb][1] = as_bf(*(const ushort8*)&b_lds[row*64 + (((4+g) ^ s7)*8)]);
    }
    #pragma unroll
    for (int mb = 0; mb < 4; mb++)
      #pragma unroll
      for (int nb = 0; nb < 4; nb++){
        acc[mb][nb] = __builtin_amdgcn_mfma_f32_16x16x32_bf16(aF[mb][0], bF[nb][0], acc[mb][nb], 0,0,0);
        acc[mb][nb] = __builtin_amdgcn_mfma_f32_16x16x32_bf16(aF[mb][1], bF[nb][1], acc[mb][nb], 0,0,0);
      }
  }
  #pragma unroll
  for (int mb = 0; mb < 4; mb++){
    #pragma unroll
    for (int nb = 0; nb < 4; nb++){
      #pragma unroll
      for (int r = 0; r < 4; r++){
        int gr = mbase + wr*64 + mb*16 + g*4 + r;
        int gc = nbase + wc*64 + nb*16 + tl;
        out[(size_t)gr*C_DIM + gc] = acc[mb][nb][r] + bo[gc];
      }
    }
  }
}

extern "C" void kernel_launch(void* const* d_in, const int* in_sizes, int n_in,
                              void* d_out, int out_size, void* d_ws, size_t ws_size,
                              hipStream_t stream){
  const float* x  = (const float*)d_in[0];
  const float* Wq = (const float*)d_in[1];
  const float* Wk = (const float*)d_in[2];
  const float* Wv = (const float*)d_in[3];
  const float* Wo = (const float*)d_in[4];
  const float* bo = (const float*)d_in[5];
  float* out = (float*)d_out;

  char* p = (char*)d_ws;
  unsigned short* xb  = (unsigned short*)p; p += (size_t)M_ROWS*C_DIM*2;   // 16MB
  unsigned short* wt  = (unsigned short*)p; p += (size_t)3*C_DIM*C_DIM*2;  // 6MB
  unsigned short* wot = (unsigned short*)p; p += (size_t)C_DIM*C_DIM*2;    // 2MB
  unsigned short* Qb  = (unsigned short*)p; p += (size_t)M_ROWS*C_DIM*2;   // 16MB
  unsigned short* Kb  = (unsigned short*)p; p += (size_t)M_ROWS*C_DIM*2;   // 16MB
  unsigned short* Vtr = (unsigned short*)p; p += (size_t)M_ROWS*C_DIM*2;   // 16MB (V^T direct)
  unsigned short* attn = xb;   // reuse: xb dead after k_gemm_qkv

  hipLaunchKernelGGL(k_conv_x, dim3(M_ROWS*C_DIM/4/256), dim3(256), 0, stream, x, xb);
  hipLaunchKernelGGL(k_pack_w, dim3(4*C_DIM*C_DIM/256), dim3(256), 0, stream,
                     Wq, Wk, Wv, Wo, wt, wot);
  hipLaunchKernelGGL(k_gemm_qkv, dim3(1536), dim3(256), 0, stream,
                     xb, wt, Qb, Kb, Vtr);
  hipLaunchKernelGGL(k_flash, dim3(256), dim3(512), 0, stream,
                     Qb, Kb, Vtr, attn);
  hipLaunchKernelGGL(k_gemm_proj, dim3(512), dim3(256), 0, stream,
                     attn, wot, bo, out);
}